// Round 2
// baseline (3095.314 us; speedup 1.0000x reference)
//
#include <hip/hip_runtime.h>
#include <hip/hip_fp16.h>

// ---------------------------------------------------------------------------
// Streaming causal-TCN decoder.
//  - 64 WGs (one per batch element) x 512 threads; each WG runs all T=32 steps.
//  - Per-block ring buffers (t-d, t-2d taps) in LDS; weights streamed from L2
//    as f16 in a fragment-friendly transposed layout (prep kernel).
//  - fp32 activations & accumulation; only weights are rounded to f16.
// ---------------------------------------------------------------------------

// ---- problem constants ----
constexpr int NBLK = 8;
constexpr int CIN  = 33;
constexpr int F    = 128;

// ---- f16 weight workspace layout (offsets in halfs) ----
constexpr int OFF_WIN  = 0;        // [3][33][128] (same layout as source)
constexpr int OFF_WRES = 12672;    // [33][128]
constexpr int OFF_W1   = 16896;    // 7 convs x 49152, ((k*16+cib)*128+ch)*8+e
constexpr int OFF_W2   = 360960;   // 8 convs x 49152
constexpr int OFF_WD0  = 754176;   // (ib*128+ch)*8+e, ib<32  (i = ib*8+e < 256)
constexpr int OFF_WD1  = 786944;   // (ib*64+ch)*8+e,  ib<16  (i < 128)
constexpr int OFF_WD2  = 795136;   // [64]
constexpr int WS_HALFS = 795200;

// ---- LDS layout (float offsets). Aliases: O_O1=O_RES, O_O2=O_C1 (disjoint lifetimes)
constexpr int O_CURX = 0;      // 36  (33 used)
constexpr int O_H    = 36;     // 128 block input / output
constexpr int O_C1   = 164;    // 128 conv1 output
constexpr int O_RES  = 292;    // 128 block0 residual
constexpr int O_HEAD = 420;    // 256 [h | enc_last]
constexpr int O_O1   = 292;    // 128 head hidden 1 (alias of O_RES)
constexpr int O_O2   = 164;    // 64  head hidden 2 (alias of O_C1)
constexpr int O_PART = 676;    // 512 reduction scratch
constexpr int O_PRED = 1188;   // 1 (+pad)
constexpr int O_IN0  = 1192;   // 2*33 ring for block0 input (+pad)
constexpr int MID_OFF[8] = {1260, 1516, 2028, 3052, 5100, 5356, 5868, 6892};
constexpr int IN_OFF[8]  = {0,    8940, 9452, 10476, 12524, 12780, 13292, 14316};
constexpr int SM_FLOATS  = 16364;   // 65456 B static LDS (< 64 KiB limit)
constexpr int DILS_[8] = {1, 2, 4, 8, 1, 2, 4, 8};

__device__ __forceinline__ float elu1(float x) { return x > 0.f ? x : expm1f(x); }

// dot of 8 f16 weights (packed in a float4) with 8 fp32 activations
__device__ __forceinline__ float dot8(float4 wv, const float* __restrict__ x) {
    const __half2* h = (const __half2*)&wv;
    float2 a = __half22float2(h[0]);
    float2 b = __half22float2(h[1]);
    float2 c = __half22float2(h[2]);
    float2 d = __half22float2(h[3]);
    float4 x0 = *(const float4*)(x);
    float4 x1 = *(const float4*)(x + 4);
    return a.x * x0.x + a.y * x0.y + b.x * x0.z + b.y * x0.w +
           c.x * x1.x + c.y * x1.y + d.x * x1.z + d.y * x1.w;
}

// Generic K=3 F->F conv over one time step. 512 threads: ch = tid&127, p = tid>>7
// splits the 128-wide input-channel range into 4x32. x0/x1/x2 = taps t-2d, t-d, t
// (nullptr => causal zero padding). Epilogue: elu(conv+bias); if FUSE_RES also
// h = elu(that + res) written to dest (dest may alias resv elementwise).
template <bool FUSE_RES>
__device__ __forceinline__ void conv_fxf(const __half* __restrict__ wblk,
                                         const float* x2, const float* x1, const float* x0,
                                         const float* __restrict__ bias,
                                         float* dest, const float* resv,
                                         float* partial, int tid) {
    const int ch = tid & 127, p = tid >> 7;
    float acc = 0.f;
    const float* xs[3] = {x0, x1, x2};
#pragma unroll
    for (int k = 0; k < 3; ++k) {
        const float* xk = xs[k];
        if (xk == nullptr) continue;  // wave-uniform (t, d uniform)
        const __half* wk = wblk + (size_t)(((k * 16 + p * 4) * 128 + ch) * 8);
        float4 wv0 = *(const float4*)(wk);
        float4 wv1 = *(const float4*)(wk + 1024);
        float4 wv2 = *(const float4*)(wk + 2048);
        float4 wv3 = *(const float4*)(wk + 3072);
        const float* xb = xk + p * 32;
        acc += dot8(wv0, xb);
        acc += dot8(wv1, xb + 8);
        acc += dot8(wv2, xb + 16);
        acc += dot8(wv3, xb + 24);
    }
    partial[tid] = acc;
    __syncthreads();
    if (tid < 128) {
        float v = partial[tid] + partial[tid + 128] + partial[tid + 256] + partial[tid + 384]
                + bias[tid];
        v = elu1(v);
        if (FUSE_RES) v = elu1(v + resv[tid]);
        dest[tid] = v;
    }
    __syncthreads();
}

// ---------------------------------------------------------------------------
// prep kernel: fp32 -> f16 with layout transform
// ---------------------------------------------------------------------------
__global__ void prep_weights(const float* __restrict__ w_in, const float* __restrict__ w_res,
                             const float* __restrict__ w1, const float* __restrict__ w2,
                             const float* __restrict__ wd0, const float* __restrict__ wd1,
                             const float* __restrict__ wd2, __half* __restrict__ dst) {
    int i = blockIdx.x * blockDim.x + threadIdx.x;
    if (i >= WS_HALFS) return;
    float v;
    if (i < OFF_WRES) {
        v = w_in[i];                       // direct copy [k][ci][ch]
    } else if (i < OFF_W1) {
        v = w_res[i - OFF_WRES];           // direct copy [ci][ch]
    } else if (i < OFF_W2) {
        int r = i - OFF_W1;
        int bb = r / 49152, q = r % 49152;
        int e = q & 7, ch = (q >> 3) & 127, kc = q >> 10;
        int k = kc >> 4, cib = kc & 15;
        v = w1[((size_t)(bb * 3 + k) * 128 + cib * 8 + e) * 128 + ch];
    } else if (i < OFF_WD0) {
        int r = i - OFF_W2;
        int bb = r / 49152, q = r % 49152;
        int e = q & 7, ch = (q >> 3) & 127, kc = q >> 10;
        int k = kc >> 4, cib = kc & 15;
        v = w2[((size_t)(bb * 3 + k) * 128 + cib * 8 + e) * 128 + ch];
    } else if (i < OFF_WD1) {
        int r = i - OFF_WD0;
        int e = r & 7, ch = (r >> 3) & 127, ib = r >> 10;
        v = wd0[(ib * 8 + e) * 128 + ch];
    } else if (i < OFF_WD2) {
        int r = i - OFF_WD1;
        int e = r & 7, ch = (r >> 3) & 63, ib = r >> 9;
        v = wd1[(ib * 8 + e) * 64 + ch];
    } else {
        v = wd2[i - OFF_WD2];
    }
    dst[i] = __float2half(v);
}

// ---------------------------------------------------------------------------
// main kernel: one WG per batch element, loops over the 32 autoregressive steps
// ---------------------------------------------------------------------------
__global__ __launch_bounds__(512) void decoder_stream(
    const float* __restrict__ enc, const float* __restrict__ dec,
    const float* __restrict__ last_y, const __half* __restrict__ wsh,
    const float* __restrict__ b_in, const float* __restrict__ b_res,
    const float* __restrict__ b1, const float* __restrict__ b2,
    const float* __restrict__ bd0, const float* __restrict__ bd1,
    const float* __restrict__ bd2, float* __restrict__ out) {
    __shared__ float sm[SM_FLOATS];
    const int tid = threadIdx.x;
    const int b = blockIdx.x;

    // init: enc_last into head buffer tail; x[0] = [dec[b,0,:], last_y[b]]
    if (tid < 128) sm[O_HEAD + 128 + tid] = enc[((size_t)b * 128 + 127) * 128 + tid];
    if (tid < 32) sm[O_CURX + tid] = dec[((size_t)b * 32 + 0) * 32 + tid];
    if (tid == 32) sm[O_CURX + 32] = last_y[b];
    __syncthreads();

    for (int t = 0; t < 32; ++t) {
        // ---------------- block 0 (33-ch input) ----------------
        {
            if (tid < 128) {  // conv_in: 3x33 taps, d=1
                float acc = 0.f;
                const float* xs[3] = {
                    (t >= 2) ? &sm[O_IN0 + (t & 1) * 33] : nullptr,
                    (t >= 1) ? &sm[O_IN0 + ((t - 1) & 1) * 33] : nullptr,
                    &sm[O_CURX]};
#pragma unroll
                for (int k = 0; k < 3; ++k) {
                    const float* xk = xs[k];
                    if (xk == nullptr) continue;
                    for (int ci = 0; ci < 33; ++ci)
                        acc += __half2float(wsh[OFF_WIN + (k * 33 + ci) * 128 + tid]) * xk[ci];
                }
                acc += b_in[tid];
                sm[O_C1 + tid] = elu1(acc);
            } else if (tid < 256) {  // 1x1 residual conv (no elu)
                int ch = tid - 128;
                float acc = 0.f;
                for (int ci = 0; ci < 33; ++ci)
                    acc += __half2float(wsh[OFF_WRES + ci * 128 + ch]) * sm[O_CURX + ci];
                sm[O_RES + ch] = acc + b_res[ch];
            }
            __syncthreads();
            if (tid < 33) sm[O_IN0 + (t & 1) * 33 + tid] = sm[O_CURX + tid];  // push ring
            // conv2 (d=1) fused with residual: h = elu(elu(conv+b2)+res) -> O_H
            const float* m1 = (t >= 1) ? &sm[MID_OFF[0] + ((t - 1) & 1) * 128] : nullptr;
            const float* m0 = (t >= 2) ? &sm[MID_OFF[0] + (t & 1) * 128] : nullptr;
            conv_fxf<true>(wsh + OFF_W2, &sm[O_C1], m1, m0, b2, &sm[O_H], &sm[O_RES],
                           &sm[O_PART], tid);
            if (tid < 128) sm[MID_OFF[0] + (t & 1) * 128 + tid] = sm[O_C1 + tid];
            __syncthreads();
        }

        // ---------------- blocks 1..7 ----------------
#pragma unroll
        for (int blk = 1; blk < NBLK; ++blk) {
            const int d = DILS_[blk];
            const int m = 2 * d;  // ring depth (power of two)
            const float* x1 = (t >= d) ? &sm[IN_OFF[blk] + ((t - d) & (m - 1)) * 128] : nullptr;
            const float* x0 = (t >= 2 * d) ? &sm[IN_OFF[blk] + (t & (m - 1)) * 128] : nullptr;
            conv_fxf<false>(wsh + OFF_W1 + (size_t)(blk - 1) * 49152, &sm[O_H], x1, x0,
                            b1 + (blk - 1) * 128, &sm[O_C1], nullptr, &sm[O_PART], tid);
            if (tid < 128) sm[IN_OFF[blk] + (t & (m - 1)) * 128 + tid] = sm[O_H + tid];
            const float* m1 = (t >= d) ? &sm[MID_OFF[blk] + ((t - d) & (m - 1)) * 128] : nullptr;
            const float* m0 = (t >= 2 * d) ? &sm[MID_OFF[blk] + (t & (m - 1)) * 128] : nullptr;
            // conv2 fused with residual (res = old h), written in place to O_H
            conv_fxf<true>(wsh + OFF_W2 + (size_t)blk * 49152, &sm[O_C1], m1, m0,
                           b2 + blk * 128, &sm[O_H], &sm[O_H], &sm[O_PART], tid);
            if (tid < 128) sm[MID_OFF[blk] + (t & (m - 1)) * 128 + tid] = sm[O_C1 + tid];
            __syncthreads();
        }

        // ---------------- head ----------------
        if (tid < 128) sm[O_HEAD + tid] = sm[O_H + tid];
        __syncthreads();
        {  // d0: 256 -> 128, elu
            const int ch = tid & 127, p = tid >> 7;
            float acc = 0.f;
            const __half* wk = wsh + OFF_WD0 + (size_t)((p * 8) * 128 + ch) * 8;
            const float* xb = &sm[O_HEAD + p * 64];
#pragma unroll
            for (int j = 0; j < 8; ++j) {
                float4 wv = *(const float4*)(wk + j * 1024);
                acc += dot8(wv, xb + j * 8);
            }
            sm[O_PART + tid] = acc;
            __syncthreads();
            if (tid < 128) {
                float v = sm[O_PART + tid] + sm[O_PART + tid + 128] + sm[O_PART + tid + 256] +
                          sm[O_PART + tid + 384] + bd0[tid];
                sm[O_O1 + tid] = elu1(v);
            }
            __syncthreads();
        }
        {  // d1: 128 -> 64, elu
            const int c6 = tid & 63, p8 = tid >> 6;
            const __half* wk = wsh + OFF_WD1 + (size_t)((p8 * 2) * 64 + c6) * 8;
            const float* xb = &sm[O_O1 + p8 * 16];
            float4 wv0 = *(const float4*)(wk);
            float4 wv1 = *(const float4*)(wk + 512);
            float acc = dot8(wv0, xb) + dot8(wv1, xb + 8);
            sm[O_PART + tid] = acc;
            __syncthreads();
            if (tid < 64) {
                float v = 0.f;
#pragma unroll
                for (int q = 0; q < 8; ++q) v += sm[O_PART + tid + q * 64];
                sm[O_O2 + tid] = elu1(v + bd1[tid]);
            }
            __syncthreads();
        }
        // d2: 64 -> 1
        if (tid < 64) {
            float v = sm[O_O2 + tid] * __half2float(wsh[OFF_WD2 + tid]);
#pragma unroll
            for (int off = 32; off > 0; off >>= 1) v += __shfl_down(v, off, 64);
            if (tid == 0) {
                float pr = v + bd2[0];
                sm[O_PRED] = pr;
                out[b * 32 + t] = pr;
            }
        }
        __syncthreads();

        // next step input
        if (t < 31) {
            if (tid < 32) sm[O_CURX + tid] = dec[((size_t)b * 32 + t + 1) * 32 + tid];
            if (tid == 32) sm[O_CURX + 32] = sm[O_PRED];
            __syncthreads();
        }
    }
}

extern "C" void kernel_launch(void* const* d_in, const int* in_sizes, int n_in,
                              void* d_out, int out_size, void* d_ws, size_t ws_size,
                              hipStream_t stream) {
    const float* enc    = (const float*)d_in[0];
    const float* dec    = (const float*)d_in[1];
    const float* last_y = (const float*)d_in[2];
    const float* w_in   = (const float*)d_in[3];
    const float* b_in   = (const float*)d_in[4];
    const float* w_res  = (const float*)d_in[5];
    const float* b_res  = (const float*)d_in[6];
    const float* w1     = (const float*)d_in[7];
    const float* b1     = (const float*)d_in[8];
    const float* w2     = (const float*)d_in[9];
    const float* b2     = (const float*)d_in[10];
    const float* wd0    = (const float*)d_in[11];
    const float* bd0    = (const float*)d_in[12];
    const float* wd1    = (const float*)d_in[13];
    const float* bd1    = (const float*)d_in[14];
    const float* wd2    = (const float*)d_in[15];
    const float* bd2    = (const float*)d_in[16];
    float* out = (float*)d_out;
    __half* wsh = (__half*)d_ws;

    prep_weights<<<(WS_HALFS + 255) / 256, 256, 0, stream>>>(w_in, w_res, w1, w2, wd0, wd1,
                                                             wd2, wsh);
    decoder_stream<<<64, 512, 0, stream>>>(enc, dec, last_y, wsh, b_in, b_res, b1, b2, bd0,
                                           bd1, bd2, out);
}

// Round 7
// 2363.099 us; speedup vs baseline: 1.3099x; 1.3099x over previous
//
#include <hip/hip_runtime.h>
#include <hip/hip_fp16.h>

// ---------------------------------------------------------------------------
// Streaming causal-TCN decoder, round 3 (= round 2 + MID[7] ring-index fix).
//  - 64 WGs (1/batch) x 512 threads, 32 sequential steps in-kernel.
//  - Wave-local conv: lane = (16 out-ch) x (4 K-slices); shfl_xor reduce.
//  - One-conv-ahead weight prefetch into named register sets (A/B).
//  - Zero-filled LDS rings => unconditional taps == exact causal padding.
//  - f16 weights (prep kernel re-layouts), fp32 activations.
// ---------------------------------------------------------------------------

// ---- f16 weight workspace layout (offsets in halfs) ----
// row = 128ch x 8e = 1024 halfs (d1: 64ch x 8e = 512)
// main conv (K=3,128->128): ((k*4+ks)*4 + j)*1024 + ch*8 + e ; ci = j*32+ks*8+e
constexpr int OFF_WIN  = 0;       // conv_in : 3 taps x (ks*2+j) rows, ci<64 pad, 24576
constexpr int OFF_WRES = 24576;   // res 1x1 : (ks*2+j) rows, ci<64 pad, 8192
constexpr int OFF_W1   = 32768;   // 7 x 49152
constexpr int OFF_W2   = 376832;  // 8 x 49152
constexpr int OFF_WD0  = 770048;  // (ks*8+j) rows, K=256, 32768
constexpr int OFF_WD1  = 802816;  // (ks8*2+j)*512 + ch64*8, K=128, 8192
constexpr int OFF_WD2  = 811008;  // 64
constexpr int WS_HALFS = 811072;

// ---- LDS float offsets ----
constexpr int O_CURX = 0;      // 64 (33 used, pad zero)
constexpr int O_ENC  = 64;     // 128
constexpr int O_H0   = 192;    // 128
constexpr int O_H1   = 320;    // 128
constexpr int O_C1A  = 448;    // 128
constexpr int O_C1B  = 576;    // 128
constexpr int O_RES  = 704;    // 128
constexpr int O_O1   = 832;    // 128
constexpr int O_O2   = 960;    // 64
constexpr int O_IN0  = 1024;   // 2 x 64 block0-input ring
constexpr int O_IN1  = 1152;   // IN rings blk1..7: depths 4,8,16,2,4,8,16 (x128)
constexpr int O_MID0 = 8576;   // MID rings blk0..7: depths 2,4,8,16,2,4,8,16 (x128)
constexpr int SM_FLOATS = 16256;  // 65024 B

__device__ __forceinline__ float elu1(float x) { return x > 0.f ? x : expm1f(x); }

struct W4 { float4 v[4]; };
struct W2 { float4 v[2]; };

__device__ __forceinline__ void load4(W4& w, const __half* p) {
#pragma unroll
    for (int j = 0; j < 4; ++j) w.v[j] = *(const float4*)(p + j * 1024);
}
__device__ __forceinline__ void load2(W2& w, const __half* p, int stride) {
#pragma unroll
    for (int j = 0; j < 2; ++j) w.v[j] = *(const float4*)(p + j * stride);
}

// dot of 8 f16 weights (one float4) with 8 fp32 LDS activations
__device__ __forceinline__ float dot8(float4 wv, const float* x) {
    const __half2* h = (const __half2*)&wv;
    float2 a = __half22float2(h[0]);
    float2 b = __half22float2(h[1]);
    float2 c = __half22float2(h[2]);
    float2 d = __half22float2(h[3]);
    float4 x0 = *(const float4*)(x);
    float4 x1 = *(const float4*)(x + 4);
    return a.x * x0.x + a.y * x0.y + b.x * x0.z + b.y * x0.w +
           c.x * x1.x + c.y * x1.y + d.x * x1.z + d.y * x1.w;
}
__device__ __forceinline__ float dot4j(const W4& w, const float* x, int ks) {
    float a = dot8(w.v[0], x + ks * 8);
    a += dot8(w.v[1], x + 32 + ks * 8);
    a += dot8(w.v[2], x + 64 + ks * 8);
    a += dot8(w.v[3], x + 96 + ks * 8);
    return a;
}
__device__ __forceinline__ float dot2j(const W2& w, const float* x, int ks) {
    return dot8(w.v[0], x + ks * 8) + dot8(w.v[1], x + 32 + ks * 8);
}

__device__ __forceinline__ void loadMain(W4& w0, W4& w1, W4& w2, const __half* base_lane, int ks) {
    load4(w0, base_lane + (ks * 4) * 1024);
    load4(w1, base_lane + ((4 + ks) * 4) * 1024);
    load4(w2, base_lane + ((8 + ks) * 4) * 1024);
}

// taps: x0 = t-2d, x1 = t-d, x2 = t (zero-filled rings => no guards)
template <bool FUSE>
__device__ __forceinline__ void computeMain(const W4& w0, const W4& w1, const W4& w2,
                                            const float* x2, const float* x1, const float* x0,
                                            const float* __restrict__ bias, float* dest,
                                            const float* resv, int ch, int ks, int lane) {
    float acc = dot4j(w0, x0, ks) + dot4j(w1, x1, ks) + dot4j(w2, x2, ks);
    acc += __shfl_xor(acc, 16, 64);
    acc += __shfl_xor(acc, 32, 64);
    float v = elu1(acc + bias[ch]);
    if (FUSE) v = elu1(v + resv[ch]);
    if (lane < 16) dest[ch] = v;
}

// ---------------------------------------------------------------------------
// prep kernel: fp32 -> f16 with layout transform (+ K padding with zeros)
// ---------------------------------------------------------------------------
__global__ void prep_weights(const float* __restrict__ w_in, const float* __restrict__ w_res,
                             const float* __restrict__ w1, const float* __restrict__ w2,
                             const float* __restrict__ wd0, const float* __restrict__ wd1,
                             const float* __restrict__ wd2, __half* __restrict__ dst) {
    int i = blockIdx.x * blockDim.x + threadIdx.x;
    if (i >= WS_HALFS) return;
    float v = 0.f;
    if (i < OFF_WRES) {
        int q = i, e = q & 7, ch = (q >> 3) & 127, row = (q >> 10) & 7, k = q >> 13;
        int ks = row >> 1, j = row & 1, ci = j * 32 + ks * 8 + e;
        v = (ci < 33) ? w_in[(k * 33 + ci) * 128 + ch] : 0.f;
    } else if (i < OFF_W1) {
        int q = i - OFF_WRES, e = q & 7, ch = (q >> 3) & 127, row = (q >> 10) & 7;
        int ks = row >> 1, j = row & 1, ci = j * 32 + ks * 8 + e;
        v = (ci < 33) ? w_res[ci * 128 + ch] : 0.f;
    } else if (i < OFF_W2) {
        int r = i - OFF_W1, bb = r / 49152, q = r % 49152;
        int e = q & 7, ch = (q >> 3) & 127, row = (q >> 10) & 15, k = q >> 14;
        int ks = row >> 2, j = row & 3, ci = j * 32 + ks * 8 + e;
        v = w1[((size_t)(bb * 3 + k) * 128 + ci) * 128 + ch];
    } else if (i < OFF_WD0) {
        int r = i - OFF_W2, bb = r / 49152, q = r % 49152;
        int e = q & 7, ch = (q >> 3) & 127, row = (q >> 10) & 15, k = q >> 14;
        int ks = row >> 2, j = row & 3, ci = j * 32 + ks * 8 + e;
        v = w2[((size_t)(bb * 3 + k) * 128 + ci) * 128 + ch];
    } else if (i < OFF_WD1) {
        int q = i - OFF_WD0, e = q & 7, ch = (q >> 3) & 127, row = (q >> 10) & 31;
        int ks = row >> 3, j = row & 7, ci = j * 32 + ks * 8 + e;
        v = wd0[ci * 128 + ch];
    } else if (i < OFF_WD2) {
        int q = i - OFF_WD1, e = q & 7, ch = (q >> 3) & 63, row = (q >> 9) & 15;
        int ks8 = row >> 1, j = row & 1, ci = j * 64 + ks8 * 8 + e;
        v = wd1[ci * 64 + ch];
    } else {
        v = wd2[i - OFF_WD2];
    }
    dst[i] = __float2half(v);
}

// ---------------------------------------------------------------------------
// main kernel
// ---------------------------------------------------------------------------
__global__ __launch_bounds__(512) void decoder_stream(
    const float* __restrict__ enc, const float* __restrict__ dec,
    const float* __restrict__ last_y, const __half* __restrict__ wsh,
    const float* __restrict__ b_in, const float* __restrict__ b_res,
    const float* __restrict__ b1, const float* __restrict__ b2,
    const float* __restrict__ bd0, const float* __restrict__ bd1,
    const float* __restrict__ bd2, float* __restrict__ out) {
    __shared__ float sm[SM_FLOATS];
    const int tid = threadIdx.x;
    const int b = blockIdx.x;
    const int lane = tid & 63;
    const int wv = tid >> 6;                 // 0..7
    const int ch = wv * 16 + (lane & 15);    // 0..127
    const int ks = lane >> 4;                // 0..3
    const int ch64 = wv * 8 + (lane & 7);    // 0..63
    const int ks8 = lane >> 3;               // 0..7

    // zero all LDS (rings + CURX padding must be 0), then init inputs
    for (int i = tid; i < SM_FLOATS; i += 512) sm[i] = 0.f;
    __syncthreads();
    if (tid < 128) sm[O_ENC + tid] = enc[((size_t)b * 128 + 127) * 128 + tid];
    if (tid < 32) sm[O_CURX + tid] = dec[((size_t)b * 32 + 0) * 32 + tid];
    if (tid == 32) sm[O_CURX + 32] = last_y[b];
    __syncthreads();

    const float bd2v = bd2[0];
    const float wd2r = (tid < 64) ? __half2float(wsh[OFF_WD2 + tid]) : 0.f;

    // weight register sets
    W4 A0, A1, A2, B0, B1, B2;
    W2 ia0, ia1, ia2, ir, D1w;

    // initial S0 weights
    {
        const __half* wl = wsh + OFF_WIN + ch * 8;
        load2(ia0, wl + (ks * 2) * 1024, 1024);
        load2(ia1, wl + (8 + ks * 2) * 1024, 1024);
        load2(ia2, wl + (16 + ks * 2) * 1024, 1024);
        load2(ir, wsh + OFF_WRES + ch * 8 + (ks * 2) * 1024, 1024);
    }

#pragma unroll 1
    for (int t = 0; t < 32; ++t) {
        // ---------- S0: conv_in + res (input = CURX, 64-padded) ----------
        {
            loadMain(B0, B1, B2, wsh + OFF_W2 + ch * 8, ks);  // prefetch conv2(blk0)
            const float* x1 = &sm[O_IN0 + ((t - 1) & 1) * 64];
            const float* x0 = &sm[O_IN0 + (t & 1) * 64];
            float aC = dot2j(ia0, x0, ks) + dot2j(ia1, x1, ks) + dot2j(ia2, &sm[O_CURX], ks);
            float aR = dot2j(ir, &sm[O_CURX], ks);
            aC += __shfl_xor(aC, 16, 64); aC += __shfl_xor(aC, 32, 64);
            aR += __shfl_xor(aR, 16, 64); aR += __shfl_xor(aR, 32, 64);
            if (lane < 16) {
                sm[O_C1A + ch] = elu1(aC + b_in[ch]);
                sm[O_RES + ch] = aR + b_res[ch];
            }
            __syncthreads();
        }
        // ---------- S1: conv2(blk0), d=1, res = O_RES -> H1 ----------
        {
            loadMain(A0, A1, A2, wsh + OFF_W1 + ch * 8, ks);  // prefetch conv1(blk1)
            if (tid < 64) sm[O_IN0 + (t & 1) * 64 + tid] = sm[O_CURX + tid];  // push IN0
            const float* m1 = &sm[O_MID0 + ((t - 1) & 1) * 128];
            const float* m0 = &sm[O_MID0 + (t & 1) * 128];
            computeMain<true>(B0, B1, B2, &sm[O_C1A], m1, m0, b2, &sm[O_H1], &sm[O_RES],
                              ch, ks, lane);
            __syncthreads();
        }
        // ---------- blocks 1..7 ----------
        int inB = O_IN1, midBprev = O_MID0, midB = O_MID0 + 256, mprev = 2;
#pragma unroll 1
        for (int blk = 1; blk < 8; ++blk) {
            const int d = 1 << (blk & 3);
            const int m = 2 * d;
            const int p = blk & 1;
            float* Hp = &sm[p ? O_H1 : O_H0];
            float* Hq = &sm[p ? O_H0 : O_H1];
            float* C1p = &sm[p ? O_C1B : O_C1A];
            float* C1q = &sm[p ? O_C1A : O_C1B];
            // conv1(blk): uses A; prefetch B = conv2(blk)
            loadMain(B0, B1, B2, wsh + OFF_W2 + blk * 49152 + ch * 8, ks);
            if (tid < 128) sm[midBprev + (t & (mprev - 1)) * 128 + tid] = C1q[tid];  // push MID[blk-1]
            {
                const float* x1 = &sm[inB + ((t - d) & (m - 1)) * 128];
                const float* x0 = &sm[inB + (t & (m - 1)) * 128];
                computeMain<false>(A0, A1, A2, Hp, x1, x0, b1 + (blk - 1) * 128, C1p, Hp,
                                   ch, ks, lane);
            }
            __syncthreads();
            // conv2(blk): uses B; prefetch A = conv1(blk+1) or d0
            if (blk < 7) {
                loadMain(A0, A1, A2, wsh + OFF_W1 + blk * 49152 + ch * 8, ks);
            } else {
                const __half* pd0 = wsh + OFF_WD0 + ch * 8;
                load4(A0, pd0 + (ks * 8) * 1024);
                load4(A1, pd0 + (ks * 8 + 4) * 1024);
            }
            if (tid < 128) sm[inB + (t & (m - 1)) * 128 + tid] = Hp[tid];  // push IN[blk]
            {
                const float* m1 = &sm[midB + ((t - d) & (m - 1)) * 128];
                const float* m0 = &sm[midB + (t & (m - 1)) * 128];
                computeMain<true>(B0, B1, B2, C1p, m1, m0, b2 + blk * 128, Hq, Hp,
                                  ch, ks, lane);
            }
            __syncthreads();
            inB += m * 128; midBprev = midB; midB += m * 128; mprev = m;
        }
        // ---------- d0: [H0 | enc] -> O_O1 ----------
        {
            const __half* pd1 = wsh + OFF_WD1 + ch64 * 8 + (ks8 * 2) * 512;  // prefetch d1
            load2(D1w, pd1, 512);
            // push MID[7] (16-deep ring: mprev==16 here; (t&31) was the round-2 OOB bug)
            if (tid < 128) sm[midBprev + (t & (mprev - 1)) * 128 + tid] = sm[O_C1B + tid];
            float acc = dot4j(A0, &sm[O_H0], ks) + dot4j(A1, &sm[O_ENC], ks);
            acc += __shfl_xor(acc, 16, 64);
            acc += __shfl_xor(acc, 32, 64);
            if (lane < 16) sm[O_O1 + ch] = elu1(acc + bd0[ch]);
            __syncthreads();
        }
        // ---------- d1: O_O1 -> O_O2 ; stage next dec row ; prefetch S0 ----------
        {
            const __half* wl = wsh + OFF_WIN + ch * 8;
            load2(ia0, wl + (ks * 2) * 1024, 1024);
            load2(ia1, wl + (8 + ks * 2) * 1024, 1024);
            load2(ia2, wl + (16 + ks * 2) * 1024, 1024);
            load2(ir, wsh + OFF_WRES + ch * 8 + (ks * 2) * 1024, 1024);
            float acc = dot8(D1w.v[0], &sm[O_O1 + ks8 * 8]) +
                        dot8(D1w.v[1], &sm[O_O1 + 64 + ks8 * 8]);
            acc += __shfl_xor(acc, 8, 64);
            acc += __shfl_xor(acc, 16, 64);
            acc += __shfl_xor(acc, 32, 64);
            if (lane < 8) sm[O_O2 + ch64] = elu1(acc + bd1[ch64]);
            int tn = t < 31 ? t + 1 : 31;
            if (tid < 32) sm[O_CURX + tid] = dec[((size_t)b * 32 + tn) * 32 + tid];
            __syncthreads();
        }
        // ---------- d2: O_O2 -> pred ----------
        if (tid < 64) {
            float v = sm[O_O2 + tid] * wd2r;
#pragma unroll
            for (int off = 32; off; off >>= 1) v += __shfl_xor(v, off, 64);
            if (tid == 0) {
                float pr = v + bd2v;
                out[b * 32 + t] = pr;
                sm[O_CURX + 32] = pr;
            }
        }
        __syncthreads();
    }
}

extern "C" void kernel_launch(void* const* d_in, const int* in_sizes, int n_in,
                              void* d_out, int out_size, void* d_ws, size_t ws_size,
                              hipStream_t stream) {
    const float* enc    = (const float*)d_in[0];
    const float* dec    = (const float*)d_in[1];
    const float* last_y = (const float*)d_in[2];
    const float* w_in   = (const float*)d_in[3];
    const float* b_in   = (const float*)d_in[4];
    const float* w_res  = (const float*)d_in[5];
    const float* b_res  = (const float*)d_in[6];
    const float* w1     = (const float*)d_in[7];
    const float* b1     = (const float*)d_in[8];
    const float* w2     = (const float*)d_in[9];
    const float* b2     = (const float*)d_in[10];
    const float* wd0    = (const float*)d_in[11];
    const float* bd0    = (const float*)d_in[12];
    const float* wd1    = (const float*)d_in[13];
    const float* bd1    = (const float*)d_in[14];
    const float* wd2    = (const float*)d_in[15];
    const float* bd2    = (const float*)d_in[16];
    float* out = (float*)d_out;
    __half* wsh = (__half*)d_ws;

    prep_weights<<<(WS_HALFS + 255) / 256, 256, 0, stream>>>(w_in, w_res, w1, w2, wd0, wd1,
                                                             wd2, wsh);
    decoder_stream<<<64, 512, 0, stream>>>(enc, dec, last_y, wsh, b_in, b_res, b1, b2, bd0,
                                           bd1, bd2, out);
}

// Round 9
// 1461.731 us; speedup vs baseline: 2.1176x; 1.6166x over previous
//
#include <hip/hip_runtime.h>
#include <hip/hip_fp16.h>

// ---------------------------------------------------------------------------
// Streaming causal-TCN decoder, round 8 (resubmit).
//  = round 3 kernel with in-loop __syncthreads() replaced by a no-vmcnt-drain
//    barrier (lgkmcnt(0) + s_barrier + sched_barrier pins), so the
//    one-conv-ahead weight prefetch actually stays in flight across phases.
//  - 64 WGs (1/batch) x 512 threads, 32 sequential steps in-kernel.
//  - Wave-local conv: lane = (16 out-ch) x (4 K-slices); shfl_xor reduce.
//  - Zero-filled LDS rings => unconditional taps == exact causal padding.
//  - f16 weights (prep kernel re-layouts), fp32 activations.
// ---------------------------------------------------------------------------

// ---- f16 weight workspace layout (offsets in halfs) ----
// row = 128ch x 8e = 1024 halfs (d1: 64ch x 8e = 512)
// main conv (K=3,128->128): ((k*4+ks)*4 + j)*1024 + ch*8 + e ; ci = j*32+ks*8+e
constexpr int OFF_WIN  = 0;       // conv_in : 3 taps x (ks*2+j) rows, ci<64 pad, 24576
constexpr int OFF_WRES = 24576;   // res 1x1 : (ks*2+j) rows, ci<64 pad, 8192
constexpr int OFF_W1   = 32768;   // 7 x 49152
constexpr int OFF_W2   = 376832;  // 8 x 49152
constexpr int OFF_WD0  = 770048;  // (ks*8+j) rows, K=256, 32768
constexpr int OFF_WD1  = 802816;  // (ks8*2+j)*512 + ch64*8, K=128, 8192
constexpr int OFF_WD2  = 811008;  // 64
constexpr int WS_HALFS = 811072;

// ---- LDS float offsets ----
constexpr int O_CURX = 0;      // 64 (33 used, pad zero)
constexpr int O_ENC  = 64;     // 128
constexpr int O_H0   = 192;    // 128
constexpr int O_H1   = 320;    // 128
constexpr int O_C1A  = 448;    // 128
constexpr int O_C1B  = 576;    // 128
constexpr int O_RES  = 704;    // 128
constexpr int O_O1   = 832;    // 128
constexpr int O_O2   = 960;    // 64
constexpr int O_IN0  = 1024;   // 2 x 64 block0-input ring
constexpr int O_IN1  = 1152;   // IN rings blk1..7: depths 4,8,16,2,4,8,16 (x128)
constexpr int O_MID0 = 8576;   // MID rings blk0..7: depths 2,4,8,16,2,4,8,16 (x128)
constexpr int SM_FLOATS = 16256;  // 65024 B

__device__ __forceinline__ float elu1(float x) { return x > 0.f ? x : expm1f(x); }

// Barrier WITHOUT the vmcnt(0) drain __syncthreads() would emit.
// LDS producer->consumer ordering: lgkmcnt(0) before s_barrier.
// Global weight loads (register destinations) stay in flight; the compiler's
// waitcnt pass still inserts counted vmcnt(N) before first use.
// sched_barrier(0) pins ds ops on both sides (m201-verified pattern).
__device__ __forceinline__ void bar() {
    __builtin_amdgcn_sched_barrier(0);
    asm volatile("s_waitcnt lgkmcnt(0)" ::: "memory");
    __builtin_amdgcn_s_barrier();
    __builtin_amdgcn_sched_barrier(0);
}

struct W4 { float4 v[4]; };
struct W2 { float4 v[2]; };

__device__ __forceinline__ void load4(W4& w, const __half* p) {
#pragma unroll
    for (int j = 0; j < 4; ++j) w.v[j] = *(const float4*)(p + j * 1024);
}
__device__ __forceinline__ void load2(W2& w, const __half* p, int stride) {
#pragma unroll
    for (int j = 0; j < 2; ++j) w.v[j] = *(const float4*)(p + j * stride);
}

// dot of 8 f16 weights (one float4) with 8 fp32 LDS activations
__device__ __forceinline__ float dot8(float4 wv, const float* x) {
    const __half2* h = (const __half2*)&wv;
    float2 a = __half22float2(h[0]);
    float2 b = __half22float2(h[1]);
    float2 c = __half22float2(h[2]);
    float2 d = __half22float2(h[3]);
    float4 x0 = *(const float4*)(x);
    float4 x1 = *(const float4*)(x + 4);
    return a.x * x0.x + a.y * x0.y + b.x * x0.z + b.y * x0.w +
           c.x * x1.x + c.y * x1.y + d.x * x1.z + d.y * x1.w;
}
__device__ __forceinline__ float dot4j(const W4& w, const float* x, int ks) {
    float a = dot8(w.v[0], x + ks * 8);
    a += dot8(w.v[1], x + 32 + ks * 8);
    a += dot8(w.v[2], x + 64 + ks * 8);
    a += dot8(w.v[3], x + 96 + ks * 8);
    return a;
}
__device__ __forceinline__ float dot2j(const W2& w, const float* x, int ks) {
    return dot8(w.v[0], x + ks * 8) + dot8(w.v[1], x + 32 + ks * 8);
}

__device__ __forceinline__ void loadMain(W4& w0, W4& w1, W4& w2, const __half* base_lane, int ks) {
    load4(w0, base_lane + (ks * 4) * 1024);
    load4(w1, base_lane + ((4 + ks) * 4) * 1024);
    load4(w2, base_lane + ((8 + ks) * 4) * 1024);
}

// taps: x0 = t-2d, x1 = t-d, x2 = t (zero-filled rings => no guards)
template <bool FUSE>
__device__ __forceinline__ void computeMain(const W4& w0, const W4& w1, const W4& w2,
                                            const float* x2, const float* x1, const float* x0,
                                            const float* __restrict__ bias, float* dest,
                                            const float* resv, int ch, int ks, int lane) {
    float acc = dot4j(w0, x0, ks) + dot4j(w1, x1, ks) + dot4j(w2, x2, ks);
    acc += __shfl_xor(acc, 16, 64);
    acc += __shfl_xor(acc, 32, 64);
    float v = elu1(acc + bias[ch]);
    if (FUSE) v = elu1(v + resv[ch]);
    if (lane < 16) dest[ch] = v;
}

// ---------------------------------------------------------------------------
// prep kernel: fp32 -> f16 with layout transform (+ K padding with zeros)
// ---------------------------------------------------------------------------
__global__ void prep_weights(const float* __restrict__ w_in, const float* __restrict__ w_res,
                             const float* __restrict__ w1, const float* __restrict__ w2,
                             const float* __restrict__ wd0, const float* __restrict__ wd1,
                             const float* __restrict__ wd2, __half* __restrict__ dst) {
    int i = blockIdx.x * blockDim.x + threadIdx.x;
    if (i >= WS_HALFS) return;
    float v = 0.f;
    if (i < OFF_WRES) {
        int q = i, e = q & 7, ch = (q >> 3) & 127, row = (q >> 10) & 7, k = q >> 13;
        int ks = row >> 1, j = row & 1, ci = j * 32 + ks * 8 + e;
        v = (ci < 33) ? w_in[(k * 33 + ci) * 128 + ch] : 0.f;
    } else if (i < OFF_W1) {
        int q = i - OFF_WRES, e = q & 7, ch = (q >> 3) & 127, row = (q >> 10) & 7;
        int ks = row >> 1, j = row & 1, ci = j * 32 + ks * 8 + e;
        v = (ci < 33) ? w_res[ci * 128 + ch] : 0.f;
    } else if (i < OFF_W2) {
        int r = i - OFF_W1, bb = r / 49152, q = r % 49152;
        int e = q & 7, ch = (q >> 3) & 127, row = (q >> 10) & 15, k = q >> 14;
        int ks = row >> 2, j = row & 3, ci = j * 32 + ks * 8 + e;
        v = w1[((size_t)(bb * 3 + k) * 128 + ci) * 128 + ch];
    } else if (i < OFF_WD0) {
        int r = i - OFF_W2, bb = r / 49152, q = r % 49152;
        int e = q & 7, ch = (q >> 3) & 127, row = (q >> 10) & 15, k = q >> 14;
        int ks = row >> 2, j = row & 3, ci = j * 32 + ks * 8 + e;
        v = w2[((size_t)(bb * 3 + k) * 128 + ci) * 128 + ch];
    } else if (i < OFF_WD1) {
        int q = i - OFF_WD0, e = q & 7, ch = (q >> 3) & 127, row = (q >> 10) & 31;
        int ks = row >> 3, j = row & 7, ci = j * 32 + ks * 8 + e;
        v = wd0[ci * 128 + ch];
    } else if (i < OFF_WD2) {
        int q = i - OFF_WD1, e = q & 7, ch = (q >> 3) & 63, row = (q >> 9) & 15;
        int ks8 = row >> 1, j = row & 1, ci = j * 64 + ks8 * 8 + e;
        v = wd1[ci * 64 + ch];
    } else {
        v = wd2[i - OFF_WD2];
    }
    dst[i] = __float2half(v);
}

// ---------------------------------------------------------------------------
// main kernel
// ---------------------------------------------------------------------------
__global__ __launch_bounds__(512) void decoder_stream(
    const float* __restrict__ enc, const float* __restrict__ dec,
    const float* __restrict__ last_y, const __half* __restrict__ wsh,
    const float* __restrict__ b_in, const float* __restrict__ b_res,
    const float* __restrict__ b1, const float* __restrict__ b2,
    const float* __restrict__ bd0, const float* __restrict__ bd1,
    const float* __restrict__ bd2, float* __restrict__ out) {
    __shared__ float sm[SM_FLOATS];
    const int tid = threadIdx.x;
    const int b = blockIdx.x;
    const int lane = tid & 63;
    const int wv = tid >> 6;                 // 0..7
    const int ch = wv * 16 + (lane & 15);    // 0..127
    const int ks = lane >> 4;                // 0..3
    const int ch64 = wv * 8 + (lane & 7);    // 0..63
    const int ks8 = lane >> 3;               // 0..7

    // zero all LDS (rings + CURX padding must be 0), then init inputs
    for (int i = tid; i < SM_FLOATS; i += 512) sm[i] = 0.f;
    __syncthreads();
    if (tid < 128) sm[O_ENC + tid] = enc[((size_t)b * 128 + 127) * 128 + tid];
    if (tid < 32) sm[O_CURX + tid] = dec[((size_t)b * 32 + 0) * 32 + tid];
    if (tid == 32) sm[O_CURX + 32] = last_y[b];
    __syncthreads();

    const float bd2v = bd2[0];
    const float wd2r = (tid < 64) ? __half2float(wsh[OFF_WD2 + tid]) : 0.f;

    // weight register sets
    W4 A0, A1, A2, B0, B1, B2;
    W2 ia0, ia1, ia2, ir, D1w;

    // initial S0 weights
    {
        const __half* wl = wsh + OFF_WIN + ch * 8;
        load2(ia0, wl + (ks * 2) * 1024, 1024);
        load2(ia1, wl + (8 + ks * 2) * 1024, 1024);
        load2(ia2, wl + (16 + ks * 2) * 1024, 1024);
        load2(ir, wsh + OFF_WRES + ch * 8 + (ks * 2) * 1024, 1024);
    }

#pragma unroll 1
    for (int t = 0; t < 32; ++t) {
        // ---------- S0: conv_in + res (input = CURX, 64-padded) ----------
        {
            loadMain(B0, B1, B2, wsh + OFF_W2 + ch * 8, ks);  // prefetch conv2(blk0)
            const float* x1 = &sm[O_IN0 + ((t - 1) & 1) * 64];
            const float* x0 = &sm[O_IN0 + (t & 1) * 64];
            float aC = dot2j(ia0, x0, ks) + dot2j(ia1, x1, ks) + dot2j(ia2, &sm[O_CURX], ks);
            float aR = dot2j(ir, &sm[O_CURX], ks);
            aC += __shfl_xor(aC, 16, 64); aC += __shfl_xor(aC, 32, 64);
            aR += __shfl_xor(aR, 16, 64); aR += __shfl_xor(aR, 32, 64);
            if (lane < 16) {
                sm[O_C1A + ch] = elu1(aC + b_in[ch]);
                sm[O_RES + ch] = aR + b_res[ch];
            }
            bar();
        }
        // ---------- S1: conv2(blk0), d=1, res = O_RES -> H1 ----------
        {
            loadMain(A0, A1, A2, wsh + OFF_W1 + ch * 8, ks);  // prefetch conv1(blk1)
            if (tid < 64) sm[O_IN0 + (t & 1) * 64 + tid] = sm[O_CURX + tid];  // push IN0
            const float* m1 = &sm[O_MID0 + ((t - 1) & 1) * 128];
            const float* m0 = &sm[O_MID0 + (t & 1) * 128];
            computeMain<true>(B0, B1, B2, &sm[O_C1A], m1, m0, b2, &sm[O_H1], &sm[O_RES],
                              ch, ks, lane);
            bar();
        }
        // ---------- blocks 1..7 ----------
        int inB = O_IN1, midBprev = O_MID0, midB = O_MID0 + 256, mprev = 2;
#pragma unroll 1
        for (int blk = 1; blk < 8; ++blk) {
            const int d = 1 << (blk & 3);
            const int m = 2 * d;
            const int p = blk & 1;
            float* Hp = &sm[p ? O_H1 : O_H0];
            float* Hq = &sm[p ? O_H0 : O_H1];
            float* C1p = &sm[p ? O_C1B : O_C1A];
            float* C1q = &sm[p ? O_C1A : O_C1B];
            // conv1(blk): uses A; prefetch B = conv2(blk)
            loadMain(B0, B1, B2, wsh + OFF_W2 + blk * 49152 + ch * 8, ks);
            if (tid < 128) sm[midBprev + (t & (mprev - 1)) * 128 + tid] = C1q[tid];  // push MID[blk-1]
            {
                const float* x1 = &sm[inB + ((t - d) & (m - 1)) * 128];
                const float* x0 = &sm[inB + (t & (m - 1)) * 128];
                computeMain<false>(A0, A1, A2, Hp, x1, x0, b1 + (blk - 1) * 128, C1p, Hp,
                                   ch, ks, lane);
            }
            bar();
            // conv2(blk): uses B; prefetch A = conv1(blk+1) or d0
            if (blk < 7) {
                loadMain(A0, A1, A2, wsh + OFF_W1 + blk * 49152 + ch * 8, ks);
            } else {
                const __half* pd0 = wsh + OFF_WD0 + ch * 8;
                load4(A0, pd0 + (ks * 8) * 1024);
                load4(A1, pd0 + (ks * 8 + 4) * 1024);
            }
            if (tid < 128) sm[inB + (t & (m - 1)) * 128 + tid] = Hp[tid];  // push IN[blk]
            {
                const float* m1 = &sm[midB + ((t - d) & (m - 1)) * 128];
                const float* m0 = &sm[midB + (t & (m - 1)) * 128];
                computeMain<true>(B0, B1, B2, C1p, m1, m0, b2 + blk * 128, Hq, Hp,
                                  ch, ks, lane);
            }
            bar();
            inB += m * 128; midBprev = midB; midB += m * 128; mprev = m;
        }
        // ---------- d0: [H0 | enc] -> O_O1 ----------
        {
            const __half* pd1 = wsh + OFF_WD1 + ch64 * 8 + (ks8 * 2) * 512;  // prefetch d1
            load2(D1w, pd1, 512);
            // push MID[7] (16-deep ring; mprev==16 here)
            if (tid < 128) sm[midBprev + (t & (mprev - 1)) * 128 + tid] = sm[O_C1B + tid];
            float acc = dot4j(A0, &sm[O_H0], ks) + dot4j(A1, &sm[O_ENC], ks);
            acc += __shfl_xor(acc, 16, 64);
            acc += __shfl_xor(acc, 32, 64);
            if (lane < 16) sm[O_O1 + ch] = elu1(acc + bd0[ch]);
            bar();
        }
        // ---------- d1: O_O1 -> O_O2 ; stage next dec row ; prefetch S0 ----------
        {
            const __half* wl = wsh + OFF_WIN + ch * 8;
            load2(ia0, wl + (ks * 2) * 1024, 1024);
            load2(ia1, wl + (8 + ks * 2) * 1024, 1024);
            load2(ia2, wl + (16 + ks * 2) * 1024, 1024);
            load2(ir, wsh + OFF_WRES + ch * 8 + (ks * 2) * 1024, 1024);
            float acc = dot8(D1w.v[0], &sm[O_O1 + ks8 * 8]) +
                        dot8(D1w.v[1], &sm[O_O1 + 64 + ks8 * 8]);
            acc += __shfl_xor(acc, 8, 64);
            acc += __shfl_xor(acc, 16, 64);
            acc += __shfl_xor(acc, 32, 64);
            if (lane < 8) sm[O_O2 + ch64] = elu1(acc + bd1[ch64]);
            int tn = t < 31 ? t + 1 : 31;
            if (tid < 32) sm[O_CURX + tid] = dec[((size_t)b * 32 + tn) * 32 + tid];
            bar();
        }
        // ---------- d2: O_O2 -> pred ----------
        if (tid < 64) {
            float v = sm[O_O2 + tid] * wd2r;
#pragma unroll
            for (int off = 32; off; off >>= 1) v += __shfl_xor(v, off, 64);
            if (tid == 0) {
                float pr = v + bd2v;
                out[b * 32 + t] = pr;
                sm[O_CURX + 32] = pr;
            }
        }
        bar();
    }
}

extern "C" void kernel_launch(void* const* d_in, const int* in_sizes, int n_in,
                              void* d_out, int out_size, void* d_ws, size_t ws_size,
                              hipStream_t stream) {
    const float* enc    = (const float*)d_in[0];
    const float* dec    = (const float*)d_in[1];
    const float* last_y = (const float*)d_in[2];
    const float* w_in   = (const float*)d_in[3];
    const float* b_in   = (const float*)d_in[4];
    const float* w_res  = (const float*)d_in[5];
    const float* b_res  = (const float*)d_in[6];
    const float* w1     = (const float*)d_in[7];
    const float* b1     = (const float*)d_in[8];
    const float* w2     = (const float*)d_in[9];
    const float* b2     = (const float*)d_in[10];
    const float* wd0    = (const float*)d_in[11];
    const float* bd0    = (const float*)d_in[12];
    const float* wd1    = (const float*)d_in[13];
    const float* bd1    = (const float*)d_in[14];
    const float* wd2    = (const float*)d_in[15];
    const float* bd2    = (const float*)d_in[16];
    float* out = (float*)d_out;
    __half* wsh = (__half*)d_ws;

    prep_weights<<<(WS_HALFS + 255) / 256, 256, 0, stream>>>(w_in, w_res, w1, w2, wd0, wd1,
                                                             wd2, wsh);
    decoder_stream<<<64, 512, 0, stream>>>(enc, dec, last_y, wsh, b_in, b_res, b1, b2, bd0,
                                           bd1, bd2, out);
}